// Round 5
// baseline (1578.104 us; speedup 1.0000x reference)
//
#include <hip/hip_runtime.h>
#include <cmath>

#define B_ 16
#define N_ 48

__device__ __forceinline__ float sigmoidf_(float x){ return 1.0f/(1.0f+expf(-x)); }

// ---------------------------------------------------------------------------
// K1: blocks 0..575: edge MLP, row-order, 64 edges/block (round-0 verified
//     structure, layer-2 reads mw1 rows directly).  relu2 row-major [e][c].
//     blocks 576..768: prep (A/Bm/Ab/Bb column-sums, wihT/whhT transposes).
// ---------------------------------------------------------------------------
__global__ __launch_bounds__(256) void k_mlp_prep(
    const float* __restrict__ ein, const float* __restrict__ w0, const float* __restrict__ b0,
    const float* __restrict__ w1, const float* __restrict__ b1,
    const float* __restrict__ w2, const float* __restrict__ b2,
    const float* __restrict__ wih, const float* __restrict__ whh,
    float* __restrict__ relu2,
    float* __restrict__ A, float* __restrict__ Bm,
    float* __restrict__ Ab, float* __restrict__ Bb,
    float* __restrict__ wihT, float* __restrict__ whhT)
{
    __shared__ __align__(16) float x1s[64*132];

    if (blockIdx.x >= 576){
        int idx = (blockIdx.x - 576)*256 + threadIdx.x;
        if (idx < 24576) {
            int r = idx >> 13;          // 0..2
            int c = (idx >> 6) & 127;
            int m = idx & 63;
            int t = 48 - 16*r;
            const float* src = w2 + c*4096 + m*64;
            float a = 0.f, b = 0.f;
            for (int k = 0; k < 64; k++){ float v = src[k]; if (k < t) a += v; else b += v; }
            A[idx] = a; Bm[idx] = b;
        } else if (idx < 24768) {
            int i2 = idx - 24576;
            int r = i2 >> 6, m = i2 & 63;
            int t = 48 - 16*r;
            const float* src = b2 + m*64;
            float a = 0.f, b = 0.f;
            for (int k = 0; k < 64; k++){ float v = src[k]; if (k < t) a += v; else b += v; }
            Ab[i2] = a; Bb[i2] = b;
        } else if (idx < 49344) {
            int i4 = idx - 24768;
            if (i4 < 12288) {
                int k = i4 / 192, col = i4 - k*192;
                wihT[i4] = wih[col*64 + k];
            } else {
                int i5 = i4 - 12288;
                int k = i5 / 192, col = i5 - k*192;
                whhT[i5] = whh[col*64 + k];
            }
        }
        return;
    }

    int tid = threadIdx.x;
    int et = tid & 15, o0 = (tid >> 4) * 8;
    size_t e0 = (size_t)blockIdx.x * 64;

    // ---- layer 1 ----
    float acc[4][8];
    {
        float4 ba = *(const float4*)&b0[o0];
        float4 bb = *(const float4*)&b0[o0 + 4];
        #pragma unroll
        for (int q = 0; q < 4; q++){
            acc[q][0]=ba.x; acc[q][1]=ba.y; acc[q][2]=ba.z; acc[q][3]=ba.w;
            acc[q][4]=bb.x; acc[q][5]=bb.y; acc[q][6]=bb.z; acc[q][7]=bb.w;
        }
    }
    #pragma unroll
    for (int i4 = 0; i4 < 4; i4++){
        float4 ev[4];
        #pragma unroll
        for (int q = 0; q < 4; q++)
            ev[q] = *(const float4*)&ein[(e0 + q*16 + et)*16 + i4*4];
        #pragma unroll
        for (int d = 0; d < 4; d++){
            int i = i4*4 + d;
            float4 wa = *(const float4*)&w0[i*128 + o0];
            float4 wb = *(const float4*)&w0[i*128 + o0 + 4];
            #pragma unroll
            for (int q = 0; q < 4; q++){
                float xi = (d==0) ? ev[q].x : (d==1) ? ev[q].y : (d==2) ? ev[q].z : ev[q].w;
                acc[q][0] += xi*wa.x; acc[q][1] += xi*wa.y;
                acc[q][2] += xi*wa.z; acc[q][3] += xi*wa.w;
                acc[q][4] += xi*wb.x; acc[q][5] += xi*wb.y;
                acc[q][6] += xi*wb.z; acc[q][7] += xi*wb.w;
            }
        }
    }
    #pragma unroll
    for (int q = 0; q < 4; q++){
        int el = q*16 + et;
        *(float4*)&x1s[el*132 + o0] =
            make_float4(fmaxf(acc[q][0],0.f), fmaxf(acc[q][1],0.f),
                        fmaxf(acc[q][2],0.f), fmaxf(acc[q][3],0.f));
        *(float4*)&x1s[el*132 + o0 + 4] =
            make_float4(fmaxf(acc[q][4],0.f), fmaxf(acc[q][5],0.f),
                        fmaxf(acc[q][6],0.f), fmaxf(acc[q][7],0.f));
    }
    __syncthreads();

    // ---- layer 2 (mw1 rows direct) ----
    float a2[4][8];
    {
        float4 ba = *(const float4*)&b1[o0];
        float4 bb = *(const float4*)&b1[o0 + 4];
        #pragma unroll
        for (int q = 0; q < 4; q++){
            a2[q][0]=ba.x; a2[q][1]=ba.y; a2[q][2]=ba.z; a2[q][3]=ba.w;
            a2[q][4]=bb.x; a2[q][5]=bb.y; a2[q][6]=bb.z; a2[q][7]=bb.w;
        }
    }
    for (int i4 = 0; i4 < 32; i4++){
        int i = i4*4;
        float4 w0a = *(const float4*)&w1[(size_t)(i+0)*128 + o0];
        float4 w0b = *(const float4*)&w1[(size_t)(i+0)*128 + o0 + 4];
        float4 w1a = *(const float4*)&w1[(size_t)(i+1)*128 + o0];
        float4 w1b = *(const float4*)&w1[(size_t)(i+1)*128 + o0 + 4];
        float4 w2a = *(const float4*)&w1[(size_t)(i+2)*128 + o0];
        float4 w2b = *(const float4*)&w1[(size_t)(i+2)*128 + o0 + 4];
        float4 w3a = *(const float4*)&w1[(size_t)(i+3)*128 + o0];
        float4 w3b = *(const float4*)&w1[(size_t)(i+3)*128 + o0 + 4];
        float4 xv[4];
        #pragma unroll
        for (int q = 0; q < 4; q++)
            xv[q] = *(const float4*)&x1s[(q*16 + et)*132 + i];
        #pragma unroll
        for (int q = 0; q < 4; q++){
            float4 x = xv[q];
            a2[q][0] += x.x*w0a.x + x.y*w1a.x + x.z*w2a.x + x.w*w3a.x;
            a2[q][1] += x.x*w0a.y + x.y*w1a.y + x.z*w2a.y + x.w*w3a.y;
            a2[q][2] += x.x*w0a.z + x.y*w1a.z + x.z*w2a.z + x.w*w3a.z;
            a2[q][3] += x.x*w0a.w + x.y*w1a.w + x.z*w2a.w + x.w*w3a.w;
            a2[q][4] += x.x*w0b.x + x.y*w1b.x + x.z*w2b.x + x.w*w3b.x;
            a2[q][5] += x.x*w0b.y + x.y*w1b.y + x.z*w2b.y + x.w*w3b.y;
            a2[q][6] += x.x*w0b.z + x.y*w1b.z + x.z*w2b.z + x.w*w3b.z;
            a2[q][7] += x.x*w0b.w + x.y*w1b.w + x.z*w2b.w + x.w*w3b.w;
        }
    }
    #pragma unroll
    for (int q = 0; q < 4; q++){
        size_t e = e0 + q*16 + et;
        float4 s0 = make_float4(fmaxf(a2[q][0],0.f), fmaxf(a2[q][1],0.f),
                                fmaxf(a2[q][2],0.f), fmaxf(a2[q][3],0.f));
        float4 s1 = make_float4(fmaxf(a2[q][4],0.f), fmaxf(a2[q][5],0.f),
                                fmaxf(a2[q][6],0.f), fmaxf(a2[q][7],0.f));
        *(float4*)&relu2[e*128 + o0]     = s0;
        *(float4*)&relu2[e*128 + o0 + 4] = s1;
    }
}

// ---------------------------------------------------------------------------
// K2: one block per batch (16 blocks x 1024 threads).  All 3 message-passing
// layers + readout + final sigmoid, batch state resident in LDS throughout.
// ---------------------------------------------------------------------------
__global__ __launch_bounds__(1024) void k_batch(
    const float* __restrict__ g, const float* __restrict__ h0,
    const float* __restrict__ relu2,
    const float* __restrict__ A, const float* __restrict__ Bm,
    const float* __restrict__ Ab, const float* __restrict__ Bb,
    const float* __restrict__ wihT, const float* __restrict__ whhT,
    const float* __restrict__ bih, const float* __restrict__ bhh,
    const float* __restrict__ w00, const float* __restrict__ b00,
    const float* __restrict__ w01, const float* __restrict__ b01,
    const float* __restrict__ w02, const float* __restrict__ b02,
    const float* __restrict__ w10, const float* __restrict__ b10,
    const float* __restrict__ w11, const float* __restrict__ b11,
    const float* __restrict__ w12, const float* __restrict__ b12,
    float* __restrict__ out)
{
    __shared__ __align__(16) float smem[14096];   // 56.4 KB
    float* h0s   = smem;           // [48][32]
    float* hcur  = smem + 1536;    // [48][64]
    float* maskS = smem + 4608;    // [48]
    float* sABs  = smem + 4656;    // [48][2]
    float* uv    = smem + 4752;    // 6144: U24/V24 | hstage | readout scratch
    float* aggs  = smem + 10896;   // [48][64]
    float* res   = smem + 13968;   // [128]

    const int tid = threadIdx.x;
    const int b   = blockIdx.x;
    const size_t gbs = (size_t)b*48*48;
    const size_t rbs = (size_t)b*48*48*128;

    // ---- init: h0 slab, mask, hfirst (grid-stride over 1024 threads!) ----
    for (int t = tid; t < 1536; t += 1024)
        h0s[t] = h0[(size_t)b*1536 + t];
    __syncthreads();
    if (tid < 48){
        float s = 0.f;
        for (int k = 0; k < 32; k++) s += h0s[tid*32 + k];
        maskS[tid] = (s > 0.f) ? 1.f : 0.f;
    }
    for (int t = tid; t < 3072; t += 1024){
        int n = t >> 6, c = t & 63;
        hcur[t] = (c < 32) ? h0s[n*32 + c] : 0.f;
    }
    __syncthreads();

    float* U24    = uv;           // [24][128]
    float* V24    = uv + 3072;    // [24][128]
    float* hstage = uv;           // [48][64] (post-agg reuse)

    // ================= 3 message-passing layers =================
    for (int L = 0; L < 3; L++){
        // sA/sB per target column j (plain mul-then-add, guarded vs fma-contract)
        if (tid < 96){
            int j = tid >> 1, which = tid & 1;
            int q0 = j + j/3;
            float s = 0.f;
            for (int i = 0; i < 48; i++){
                float w = g[gbs + (size_t)i*48 + j] * hcur[i*64 + q0 + which];
                asm volatile("" : "+v"(w));
                s += w;
            }
            sABs[j*2 + which] = s;
        }
        for (int jh = 0; jh < 2; jh++){
            // ---- U/V for 24 columns (i-halves summed in verified order) ----
            {
                int jl = tid >> 7, c = tid & 127;
                for (int sp = 0; sp < 3; sp++){
                    int jloc = sp*8 + jl;
                    int j = jh*24 + jloc;
                    int q0 = j + j/3;
                    const float* r2b = relu2 + rbs + (size_t)j*128 + c;  // + i*6144
                    float aU0 = 0.f, aV0 = 0.f, aU1 = 0.f, aV1 = 0.f;
                    for (int i = 0; i < 24; i++){
                        float gv = g[gbs + (size_t)i*48 + j];
                        float v  = r2b[(size_t)i*6144];
                        float wA = gv * hcur[i*64 + q0];
                        float wB = gv * hcur[i*64 + q0 + 1];
                        aU0 += wA*v; aV0 += wB*v;
                    }
                    for (int i = 24; i < 48; i++){
                        float gv = g[gbs + (size_t)i*48 + j];
                        float v  = r2b[(size_t)i*6144];
                        float wA = gv * hcur[i*64 + q0];
                        float wB = gv * hcur[i*64 + q0 + 1];
                        aU1 += wA*v; aV1 += wB*v;
                    }
                    U24[jloc*128 + c] = aU0 + aU1;
                    V24[jloc*128 + c] = aV0 + aV1;
                }
            }
            __syncthreads();
            // ---- agg = U@A_r + V@B_r + bias sums (verified 4x32 partials) ----
            {
                int jl = tid >> 6, m = tid & 63;
                for (int ap = 0; ap < 2; ap++){
                    int jloc = ap*16 + jl;
                    if (jloc < 24){
                        int j = jh*24 + jloc;
                        int r = j % 3;
                        const float* Arp = A  + r*8192 + m;
                        const float* Brp = Bm + r*8192 + m;
                        const float* Us = U24 + jloc*128;
                        const float* Vs = V24 + jloc*128;
                        float p[4];
                        #pragma unroll
                        for (int cg = 0; cg < 4; cg++){
                            float a = 0.f;
                            for (int cc = 0; cc < 32; cc++){
                                int c = cg*32 + cc;
                                a += Us[c]*Arp[c*64] + Vs[c]*Brp[c*64];
                            }
                            p[cg] = a;
                        }
                        aggs[j*64 + m] = p[0] + p[1] + p[2] + p[3]
                                       + sABs[j*2 + 0]*Ab[r*64 + m]
                                       + sABs[j*2 + 1]*Bb[r*64 + m];
                    }
                }
            }
            __syncthreads();
        }
        // ---- GRU (gates in registers; verified per-output k-order) ----
        {
            int nl = tid >> 6, m = tid & 63;
            for (int np = 0; np < 3; np++){
                int n = np*16 + nl;
                float gr = bih[m],       hr = bhh[m];
                float gz = bih[64 + m],  hz = bhh[64 + m];
                float gn = bih[128 + m], hn = bhh[128 + m];
                for (int k = 0; k < 64; k++){
                    float av = aggs[n*64 + k];
                    float hv = hcur[n*64 + k];
                    gr += av * wihT[k*192 + m];
                    gz += av * wihT[k*192 + 64 + m];
                    gn += av * wihT[k*192 + 128 + m];
                    hr += hv * whhT[k*192 + m];
                    hz += hv * whhT[k*192 + 64 + m];
                    hn += hv * whhT[k*192 + 128 + m];
                }
                float rr = sigmoidf_(gr + hr);
                float zz = sigmoidf_(gz + hz);
                float nn = tanhf(gn + rr*hn);
                float hnew = (1.f - zz)*nn + zz*hcur[n*64 + m];
                hstage[n*64 + m] = maskS[n] * hnew;
            }
        }
        __syncthreads();
        for (int t = tid; t < 3072; t += 1024)
            hcur[t] = hstage[t];
        __syncthreads();
    }

    // ================= readout (6 passes x 8 nodes) =================
    float* xcat = uv;            // [8][128]
    float* ybuf = uv + 1024;     // [8][128]
    float* y2b  = uv + 2048;     // [8][128]
    float* zbuf = uv + 3072;     // [8][128]
    float* z2b  = uv + 4096;     // [8][128]
    float* vals = uv + 5120;     // [8][128]
    const int nl = tid >> 7, o = tid & 127;

    if (tid < 128) res[tid] = 0.f;
    for (int p = 0; p < 6; p++){
        int n = p*8 + nl;
        // build gate_in = [hfirst | hT]
        xcat[nl*128 + o] = (o < 64)
            ? ((o < 32) ? h0s[n*32 + o] : 0.f)
            : hcur[n*64 + (o - 64)];
        __syncthreads();
        // phase A: Net0 L0 (dim 128) and Net1 L0 (dim 64)
        {
            float a0 = b00[o];
            for (int i = 0; i < 128; i += 4){
                float w0 = w00[(size_t)(i+0)*128 + o];
                float w1 = w00[(size_t)(i+1)*128 + o];
                float w2 = w00[(size_t)(i+2)*128 + o];
                float w3 = w00[(size_t)(i+3)*128 + o];
                const float4 x0 = *(const float4*)&xcat[nl*128 + i];
                a0 += x0.x*w0 + x0.y*w1 + x0.z*w2 + x0.w*w3;
            }
            ybuf[nl*128 + o] = fmaxf(a0, 0.f);
            float a1 = b10[o];
            for (int i = 0; i < 64; i += 4){
                float w0 = w10[(size_t)(i+0)*128 + o];
                float w1 = w10[(size_t)(i+1)*128 + o];
                float w2 = w10[(size_t)(i+2)*128 + o];
                float w3 = w10[(size_t)(i+3)*128 + o];
                const float4 x0 = *(const float4*)&xcat[nl*128 + 64 + i];
                a1 += x0.x*w0 + x0.y*w1 + x0.z*w2 + x0.w*w3;
            }
            y2b[nl*128 + o] = fmaxf(a1, 0.f);
        }
        __syncthreads();
        // phase B: Net0 L1 and Net1 L1 (dim 128)
        {
            float a0 = b01[o];
            for (int i = 0; i < 128; i += 4){
                float w0 = w01[(size_t)(i+0)*128 + o];
                float w1 = w01[(size_t)(i+1)*128 + o];
                float w2 = w01[(size_t)(i+2)*128 + o];
                float w3 = w01[(size_t)(i+3)*128 + o];
                const float4 x0 = *(const float4*)&ybuf[nl*128 + i];
                a0 += x0.x*w0 + x0.y*w1 + x0.z*w2 + x0.w*w3;
            }
            zbuf[nl*128 + o] = fmaxf(a0, 0.f);
            float a1 = b11[o];
            for (int i = 0; i < 128; i += 4){
                float w0 = w11[(size_t)(i+0)*128 + o];
                float w1 = w11[(size_t)(i+1)*128 + o];
                float w2 = w11[(size_t)(i+2)*128 + o];
                float w3 = w11[(size_t)(i+3)*128 + o];
                const float4 x0 = *(const float4*)&y2b[nl*128 + i];
                a1 += x0.x*w0 + x0.y*w1 + x0.z*w2 + x0.w*w3;
            }
            z2b[nl*128 + o] = fmaxf(a1, 0.f);
        }
        __syncthreads();
        // phase C: Net0 L2, Net1 L2 (linear) -> val
        {
            float a0 = b02[o];
            for (int i = 0; i < 128; i += 4){
                float w0 = w02[(size_t)(i+0)*128 + o];
                float w1 = w02[(size_t)(i+1)*128 + o];
                float w2 = w02[(size_t)(i+2)*128 + o];
                float w3 = w02[(size_t)(i+3)*128 + o];
                const float4 x0 = *(const float4*)&zbuf[nl*128 + i];
                a0 += x0.x*w0 + x0.y*w1 + x0.z*w2 + x0.w*w3;
            }
            float a1 = b12[o];
            for (int i = 0; i < 128; i += 4){
                float w0 = w12[(size_t)(i+0)*128 + o];
                float w1 = w12[(size_t)(i+1)*128 + o];
                float w2 = w12[(size_t)(i+2)*128 + o];
                float w3 = w12[(size_t)(i+3)*128 + o];
                const float4 x0 = *(const float4*)&z2b[nl*128 + i];
                a1 += x0.x*w0 + x0.y*w1 + x0.z*w2 + x0.w*w3;
            }
            vals[nl*128 + o] = maskS[n] * a0 * a1;
        }
        __syncthreads();
        // accumulate in the verified reduction order:
        // group partial = (v0+v2)+(v1+v3); res += partials sequentially
        if (tid < 128){
            float pe = (vals[0*128 + tid] + vals[2*128 + tid])
                     + (vals[1*128 + tid] + vals[3*128 + tid]);
            float po = (vals[4*128 + tid] + vals[6*128 + tid])
                     + (vals[5*128 + tid] + vals[7*128 + tid]);
            res[tid] = (res[tid] + pe) + po;
        }
        __syncthreads();
    }
    if (tid < 128)
        out[(size_t)b*128 + tid] = 1.0f / (1.0f + expf(-res[tid]));
}

// ---------------------------------------------------------------------------
extern "C" void kernel_launch(void* const* d_in, const int* in_sizes, int n_in,
                              void* d_out, int out_size, void* d_ws, size_t ws_size,
                              hipStream_t stream)
{
    (void)in_sizes; (void)n_in; (void)out_size; (void)ws_size;
    const float* g    = (const float*)d_in[0];
    const float* h0   = (const float*)d_in[1];
    const float* e    = (const float*)d_in[2];
    const float* mw0  = (const float*)d_in[3];
    const float* mb0  = (const float*)d_in[4];
    const float* mw1  = (const float*)d_in[5];
    const float* mb1  = (const float*)d_in[6];
    const float* mw2  = (const float*)d_in[7];
    const float* mb2  = (const float*)d_in[8];
    const float* wih  = (const float*)d_in[9];
    const float* whh  = (const float*)d_in[10];
    const float* bih  = (const float*)d_in[11];
    const float* bhh  = (const float*)d_in[12];
    const float* r0w0 = (const float*)d_in[13];
    const float* r0b0 = (const float*)d_in[14];
    const float* r0w1 = (const float*)d_in[15];
    const float* r0b1 = (const float*)d_in[16];
    const float* r0w2 = (const float*)d_in[17];
    const float* r0b2 = (const float*)d_in[18];
    const float* r1w0 = (const float*)d_in[19];
    const float* r1b0 = (const float*)d_in[20];
    const float* r1w1 = (const float*)d_in[21];
    const float* r1b1 = (const float*)d_in[22];
    const float* r1w2 = (const float*)d_in[23];
    const float* r1b2 = (const float*)d_in[24];
    float* out = (float*)d_out;

    float* ws     = (float*)d_ws;
    float* A      = ws;                  // 3*128*64   = 24576
    float* Bm     = A      + 24576;      //              24576
    float* Ab     = Bm     + 24576;      // 3*64       = 192
    float* Bb     = Ab     + 192;        //              192
    float* wihT   = Bb     + 192;        // 64*192     = 12288
    float* whhT   = wihT   + 12288;      //              12288
    float* relu2  = whhT   + 12288;      // 36864*128  = 4718592
    // total ~ 4.79M floats = 18.3 MiB

    k_mlp_prep<<<769, 256, 0, stream>>>(e, mw0, mb0, mw1, mb1, mw2, mb2,
                                        wih, whh, relu2,
                                        A, Bm, Ab, Bb, wihT, whhT);
    k_batch<<<16, 1024, 0, stream>>>(g, h0, relu2,
                                     A, Bm, Ab, Bb, wihT, whhT, bih, bhh,
                                     r0w0, r0b0, r0w1, r0b1, r0w2, r0b2,
                                     r1w0, r1b0, r1w1, r1b1, r1w2, r1b2,
                                     out);
}

// Round 6
// 222.967 us; speedup vs baseline: 7.0777x; 7.0777x over previous
//
#include <hip/hip_runtime.h>
#include <cmath>

#define B_ 16
#define N_ 48

__device__ __forceinline__ float sigmoidf_(float x){ return 1.0f/(1.0f+expf(-x)); }

// ---------------------------------------------------------------------------
// K1: blocks 0..1151: edge MLP, row-order, 32 edges/block; writes relu2T
//     in [b][j][i][c] layout (reader-contiguous).
//     blocks 1152+: prep (A/Bm/Ab/Bb sums, hfirst, mask, wihT/whhT, zero accum).
// ---------------------------------------------------------------------------
__global__ __launch_bounds__(256) void k_mlp_prep(
    const float* __restrict__ ein, const float* __restrict__ w0, const float* __restrict__ b0,
    const float* __restrict__ w1, const float* __restrict__ b1,
    const float* __restrict__ w2, const float* __restrict__ b2,
    const float* __restrict__ h0,
    const float* __restrict__ wih, const float* __restrict__ whh,
    float* __restrict__ relu2T,
    float* __restrict__ A, float* __restrict__ Bm,
    float* __restrict__ Ab, float* __restrict__ Bb,
    float* __restrict__ hfirst, float* __restrict__ mask,
    float* __restrict__ wihT, float* __restrict__ whhT,
    float* __restrict__ accum, unsigned* __restrict__ cnt)
{
    __shared__ __align__(16) float x1s[32*132];

    if (blockIdx.x >= 1152){
        int idx = (blockIdx.x - 1152)*256 + threadIdx.x;
        if (idx < 24576) {
            int r = idx >> 13;          // 0..2
            int c = (idx >> 6) & 127;
            int m = idx & 63;
            int t = 48 - 16*r;
            const float* src = w2 + c*4096 + m*64;
            float a = 0.f, b = 0.f;
            for (int k = 0; k < 64; k++){ float v = src[k]; if (k < t) a += v; else b += v; }
            A[idx] = a; Bm[idx] = b;
        } else if (idx < 24768) {
            int i2 = idx - 24576;
            int r = i2 >> 6, m = i2 & 63;
            int t = 48 - 16*r;
            const float* src = b2 + m*64;
            float a = 0.f, b = 0.f;
            for (int k = 0; k < 64; k++){ float v = src[k]; if (k < t) a += v; else b += v; }
            Ab[i2] = a; Bb[i2] = b;
        } else if (idx < 73920) {
            int i3 = idx - 24768;
            int node = i3 >> 6, m = i3 & 63;
            hfirst[i3] = (m < 32) ? h0[node*32 + m] : 0.f;
            if (m == 0) {
                float s = 0.f;
                for (int k = 0; k < 32; k++) s += h0[node*32 + k];
                mask[node] = (s > 0.f) ? 1.f : 0.f;
            }
        } else if (idx < 98496) {
            int i4 = idx - 73920;
            if (i4 < 12288) {
                int k = i4 / 192, col = i4 - k*192;
                wihT[i4] = wih[col*64 + k];
            } else {
                int i5 = i4 - 12288;
                int k = i5 / 192, col = i5 - k*192;
                whhT[i5] = whh[col*64 + k];
            }
        } else if (idx < 100544) {
            int i6 = idx - 98496;
            accum[i6] = 0.f;
        } else if (idx < 100560) {
            cnt[idx - 100544] = 0u;
        }
        return;
    }

    int tid = threadIdx.x;
    int et = tid & 15, o0 = (tid >> 4) * 8;
    size_t e0 = (size_t)blockIdx.x * 32;

    // ---- layer 1 ----
    float acc[2][8];
    {
        float4 ba = *(const float4*)&b0[o0];
        float4 bb = *(const float4*)&b0[o0 + 4];
        #pragma unroll
        for (int q = 0; q < 2; q++){
            acc[q][0]=ba.x; acc[q][1]=ba.y; acc[q][2]=ba.z; acc[q][3]=ba.w;
            acc[q][4]=bb.x; acc[q][5]=bb.y; acc[q][6]=bb.z; acc[q][7]=bb.w;
        }
    }
    #pragma unroll
    for (int i4 = 0; i4 < 4; i4++){
        float4 ev[2];
        #pragma unroll
        for (int q = 0; q < 2; q++)
            ev[q] = *(const float4*)&ein[(e0 + q*16 + et)*16 + i4*4];
        #pragma unroll
        for (int d = 0; d < 4; d++){
            int i = i4*4 + d;
            float4 wa = *(const float4*)&w0[i*128 + o0];
            float4 wb = *(const float4*)&w0[i*128 + o0 + 4];
            #pragma unroll
            for (int q = 0; q < 2; q++){
                float xi = (d==0) ? ev[q].x : (d==1) ? ev[q].y : (d==2) ? ev[q].z : ev[q].w;
                acc[q][0] += xi*wa.x; acc[q][1] += xi*wa.y;
                acc[q][2] += xi*wa.z; acc[q][3] += xi*wa.w;
                acc[q][4] += xi*wb.x; acc[q][5] += xi*wb.y;
                acc[q][6] += xi*wb.z; acc[q][7] += xi*wb.w;
            }
        }
    }
    #pragma unroll
    for (int q = 0; q < 2; q++){
        int el = q*16 + et;
        *(float4*)&x1s[el*132 + o0] =
            make_float4(fmaxf(acc[q][0],0.f), fmaxf(acc[q][1],0.f),
                        fmaxf(acc[q][2],0.f), fmaxf(acc[q][3],0.f));
        *(float4*)&x1s[el*132 + o0 + 4] =
            make_float4(fmaxf(acc[q][4],0.f), fmaxf(acc[q][5],0.f),
                        fmaxf(acc[q][6],0.f), fmaxf(acc[q][7],0.f));
    }
    __syncthreads();

    // ---- layer 2 (mw1 rows direct) ----
    float a2[2][8];
    {
        float4 ba = *(const float4*)&b1[o0];
        float4 bb = *(const float4*)&b1[o0 + 4];
        #pragma unroll
        for (int q = 0; q < 2; q++){
            a2[q][0]=ba.x; a2[q][1]=ba.y; a2[q][2]=ba.z; a2[q][3]=ba.w;
            a2[q][4]=bb.x; a2[q][5]=bb.y; a2[q][6]=bb.z; a2[q][7]=bb.w;
        }
    }
    for (int i4 = 0; i4 < 32; i4++){
        int i = i4*4;
        float4 w0a = *(const float4*)&w1[(size_t)(i+0)*128 + o0];
        float4 w0b = *(const float4*)&w1[(size_t)(i+0)*128 + o0 + 4];
        float4 w1a = *(const float4*)&w1[(size_t)(i+1)*128 + o0];
        float4 w1b = *(const float4*)&w1[(size_t)(i+1)*128 + o0 + 4];
        float4 w2a = *(const float4*)&w1[(size_t)(i+2)*128 + o0];
        float4 w2b = *(const float4*)&w1[(size_t)(i+2)*128 + o0 + 4];
        float4 w3a = *(const float4*)&w1[(size_t)(i+3)*128 + o0];
        float4 w3b = *(const float4*)&w1[(size_t)(i+3)*128 + o0 + 4];
        float4 xv[2];
        #pragma unroll
        for (int q = 0; q < 2; q++)
            xv[q] = *(const float4*)&x1s[(q*16 + et)*132 + i];
        #pragma unroll
        for (int q = 0; q < 2; q++){
            float4 x = xv[q];
            a2[q][0] += x.x*w0a.x + x.y*w1a.x + x.z*w2a.x + x.w*w3a.x;
            a2[q][1] += x.x*w0a.y + x.y*w1a.y + x.z*w2a.y + x.w*w3a.y;
            a2[q][2] += x.x*w0a.z + x.y*w1a.z + x.z*w2a.z + x.w*w3a.z;
            a2[q][3] += x.x*w0a.w + x.y*w1a.w + x.z*w2a.w + x.w*w3a.w;
            a2[q][4] += x.x*w0b.x + x.y*w1b.x + x.z*w2b.x + x.w*w3b.x;
            a2[q][5] += x.x*w0b.y + x.y*w1b.y + x.z*w2b.y + x.w*w3b.y;
            a2[q][6] += x.x*w0b.z + x.y*w1b.z + x.z*w2b.z + x.w*w3b.z;
            a2[q][7] += x.x*w0b.w + x.y*w1b.w + x.z*w2b.w + x.w*w3b.w;
        }
    }
    #pragma unroll
    for (int q = 0; q < 2; q++){
        size_t e = e0 + q*16 + et;
        int b  = (int)(e / 2304);
        int rm = (int)(e - (size_t)b*2304);
        int i  = rm / 48;
        int j  = rm - i*48;
        size_t off = (((size_t)(b*48 + j)*48) + i)*128;
        float4 s0 = make_float4(fmaxf(a2[q][0],0.f), fmaxf(a2[q][1],0.f),
                                fmaxf(a2[q][2],0.f), fmaxf(a2[q][3],0.f));
        float4 s1 = make_float4(fmaxf(a2[q][4],0.f), fmaxf(a2[q][5],0.f),
                                fmaxf(a2[q][6],0.f), fmaxf(a2[q][7],0.f));
        *(float4*)&relu2T[off + o0]     = s0;
        *(float4*)&relu2T[off + o0 + 4] = s1;
    }
}

// ---------------------------------------------------------------------------
// K2: message-passing layer; relu2T read is block-contiguous (24 KB stream).
// (R3-verified structure)
// ---------------------------------------------------------------------------
__global__ __launch_bounds__(256) void k_layer(
    const float* __restrict__ hin, float* __restrict__ hout,
    const float* __restrict__ relu2T,
    const float* __restrict__ A, const float* __restrict__ Bm,
    const float* __restrict__ Ab, const float* __restrict__ Bb,
    const float* __restrict__ g, const float* __restrict__ mask,
    const float* __restrict__ wihT, const float* __restrict__ whhT,
    const float* __restrict__ bih, const float* __restrict__ bhh)
{
    int bj = blockIdx.x;
    int b = bj / 48, j = bj - b*48;
    int r = j % 3;
    int p0 = j + j/3;
    int tid = threadIdx.x;
    int base = b*48;
    __shared__ float hs[64], wAs[48], wBs[48];
    __shared__ float pU[2][128], pV[2][128];
    __shared__ float Us[128], Vs[128];
    __shared__ float pC[4][64];
    __shared__ float sAB[2];
    __shared__ float aggs[64], gi[192], gh[192];

    if (tid < 64) hs[tid] = hin[(size_t)bj*64 + tid];
    else if (tid < 112){
        int i = tid - 64;
        int node = base + i;
        float gv = g[(size_t)node*48 + j];
        wAs[i] = gv * hin[(size_t)node*64 + p0];
        wBs[i] = gv * hin[(size_t)node*64 + p0 + 1];
    }
    __syncthreads();
    if (tid < 2){
        const float* src = tid ? wBs : wAs;
        float s = 0.f;
        for (int i = 0; i < 48; i++) s += src[i];
        sAB[tid] = s;
    }
    {
        int c = tid & 127, half = tid >> 7;
        const float* r2b = relu2T + (size_t)bj*6144 + c;   // i-stride 128
        float aU = 0.f, aV = 0.f;
        for (int ii = 0; ii < 24; ii++){
            int i = half*24 + ii;
            float v = r2b[i*128];
            aU += wAs[i]*v; aV += wBs[i]*v;
        }
        pU[half][c] = aU; pV[half][c] = aV;
    }
    __syncthreads();
    if (tid < 128){ Us[tid] = pU[0][tid] + pU[1][tid]; Vs[tid] = pV[0][tid] + pV[1][tid]; }
    __syncthreads();
    {
        int m = tid & 63, cg = tid >> 6;
        const float* Arp = A  + r*8192 + m;
        const float* Brp = Bm + r*8192 + m;
        float a = 0.f;
        for (int cc = 0; cc < 32; cc++){
            int c = cg*32 + cc;
            a += Us[c]*Arp[c*64] + Vs[c]*Brp[c*64];
        }
        pC[cg][m] = a;
    }
    __syncthreads();
    if (tid < 64){
        aggs[tid] = pC[0][tid] + pC[1][tid] + pC[2][tid] + pC[3][tid]
                  + sAB[0]*Ab[r*64 + tid] + sAB[1]*Bb[r*64 + tid];
    }
    __syncthreads();
    if (tid < 192){
        float gacc = bih[tid], hacc = bhh[tid];
        for (int k = 0; k < 64; k++){
            gacc += aggs[k] * wihT[k*192 + tid];
            hacc += hs[k]   * whhT[k*192 + tid];
        }
        gi[tid] = gacc; gh[tid] = hacc;
    }
    __syncthreads();
    if (tid < 64){
        float rr = sigmoidf_(gi[tid] + gh[tid]);
        float zz = sigmoidf_(gi[64+tid] + gh[64+tid]);
        float nn = tanhf(gi[128+tid] + rr*gh[128+tid]);
        float hnew = (1.f - zz)*nn + zz*hs[tid];
        hout[(size_t)bj*64 + tid] = mask[bj] * hnew;
    }
}

// ---------------------------------------------------------------------------
// k_read_final: readout, 192 blocks (16 batches x 12 groups of 4 nodes),
// atomic accumulate + last-block sigmoid (fused k_final).
// ---------------------------------------------------------------------------
__device__ __forceinline__ void rd_layer(
    const float* __restrict__ Xs, const float* __restrict__ W,
    const float* __restrict__ bias, float* __restrict__ Ys,
    int dim, int o, int ng, bool do_relu)
{
    float a0 = bias[o];
    float a1 = a0;
    for (int i = 0; i < dim; i += 4){
        float w0 = W[(size_t)(i+0)*128 + o];
        float w1 = W[(size_t)(i+1)*128 + o];
        float w2 = W[(size_t)(i+2)*128 + o];
        float w3 = W[(size_t)(i+3)*128 + o];
        const float4 x0 = *(const float4*)&Xs[ng*128 + i];
        const float4 x1 = *(const float4*)&Xs[(ng+2)*128 + i];
        a0 += x0.x*w0 + x0.y*w1 + x0.z*w2 + x0.w*w3;
        a1 += x1.x*w0 + x1.y*w1 + x1.z*w2 + x1.w*w3;
    }
    if (do_relu){ a0 = fmaxf(a0, 0.f); a1 = fmaxf(a1, 0.f); }
    Ys[ng*128 + o] = a0;
    Ys[(ng+2)*128 + o] = a1;
}

__global__ __launch_bounds__(256) void k_read_final(
    const float* __restrict__ hfirst, const float* __restrict__ hT,
    const float* __restrict__ mask,
    const float* __restrict__ w00, const float* __restrict__ b00,
    const float* __restrict__ w01, const float* __restrict__ b01,
    const float* __restrict__ w02, const float* __restrict__ b02,
    const float* __restrict__ w10, const float* __restrict__ b10,
    const float* __restrict__ w11, const float* __restrict__ b11,
    const float* __restrict__ w12, const float* __restrict__ b12,
    float* __restrict__ accum, unsigned* __restrict__ cnt,
    float* __restrict__ out)
{
    __shared__ __align__(16) float xs[4*128];
    __shared__ __align__(16) float ys[4*128];
    __shared__ __align__(16) float zs[4*128];
    __shared__ __align__(16) float os0[4*128];
    __shared__ float mS[4];
    __shared__ unsigned fin;
    int tid = threadIdx.x;
    int b = blockIdx.x / 12, gg = blockIdx.x - b*12;
    int node0 = b*48 + gg*4;
    int o = tid & 127, ng = tid >> 7;
    if (tid < 4) mS[tid] = mask[node0 + tid];
    for (int i = tid; i < 4*128; i += 256){
        int r = i >> 7, c = i & 127;
        xs[i] = (c < 64) ? hfirst[(size_t)(node0+r)*64 + c]
                         : hT[(size_t)(node0+r)*64 + (c - 64)];
    }
    __syncthreads();
    rd_layer(xs,      w00, b00, ys,  128, o, ng, true);  __syncthreads();
    rd_layer(ys,      w01, b01, zs,  128, o, ng, true);  __syncthreads();
    rd_layer(zs,      w02, b02, os0, 128, o, ng, false); __syncthreads();
    rd_layer(xs + 64, w10, b10, ys,  64,  o, ng, true);  __syncthreads();
    rd_layer(ys,      w11, b11, zs,  128, o, ng, true);  __syncthreads();
    {
        float a0 = b12[o];
        float a1 = a0;
        for (int i = 0; i < 128; i += 4){
            float w0 = w12[(size_t)(i+0)*128 + o];
            float w1 = w12[(size_t)(i+1)*128 + o];
            float w2 = w12[(size_t)(i+2)*128 + o];
            float w3 = w12[(size_t)(i+3)*128 + o];
            const float4 x0 = *(const float4*)&zs[ng*128 + i];
            const float4 x1 = *(const float4*)&zs[(ng+2)*128 + i];
            a0 += x0.x*w0 + x0.y*w1 + x0.z*w2 + x0.w*w3;
            a1 += x1.x*w0 + x1.y*w1 + x1.z*w2 + x1.w*w3;
        }
        float s = mS[ng]   * os0[ng*128 + o]     * a0
                + mS[ng+2] * os0[(ng+2)*128 + o] * a1;
        __syncthreads();
        ys[ng*128 + o] = s;
    }
    __syncthreads();
    // atomic accumulate this block's 128-vector into accum[b]
    if (tid < 128)
        atomicAdd(&accum[(size_t)b*128 + tid], ys[tid] + ys[128 + tid]);
    __syncthreads();              // all adds issued & drained (barrier waits vmcnt)
    if (tid == 0){
        __threadfence();          // release: adds visible before counter bump
        fin = atomicAdd(&cnt[b], 1u);
    }
    __syncthreads();
    if (fin == 11u && tid < 128){
        float v = atomicAdd(&accum[(size_t)b*128 + tid], 0.f);  // coherent fetch
        out[(size_t)b*128 + tid] = 1.0f / (1.0f + expf(-v));
    }
}

// ---------------------------------------------------------------------------
extern "C" void kernel_launch(void* const* d_in, const int* in_sizes, int n_in,
                              void* d_out, int out_size, void* d_ws, size_t ws_size,
                              hipStream_t stream)
{
    (void)in_sizes; (void)n_in; (void)out_size; (void)ws_size;
    const float* g    = (const float*)d_in[0];
    const float* h0   = (const float*)d_in[1];
    const float* e    = (const float*)d_in[2];
    const float* mw0  = (const float*)d_in[3];
    const float* mb0  = (const float*)d_in[4];
    const float* mw1  = (const float*)d_in[5];
    const float* mb1  = (const float*)d_in[6];
    const float* mw2  = (const float*)d_in[7];
    const float* mb2  = (const float*)d_in[8];
    const float* wih  = (const float*)d_in[9];
    const float* whh  = (const float*)d_in[10];
    const float* bih  = (const float*)d_in[11];
    const float* bhh  = (const float*)d_in[12];
    const float* r0w0 = (const float*)d_in[13];
    const float* r0b0 = (const float*)d_in[14];
    const float* r0w1 = (const float*)d_in[15];
    const float* r0b1 = (const float*)d_in[16];
    const float* r0w2 = (const float*)d_in[17];
    const float* r0b2 = (const float*)d_in[18];
    const float* r1w0 = (const float*)d_in[19];
    const float* r1b0 = (const float*)d_in[20];
    const float* r1w1 = (const float*)d_in[21];
    const float* r1b1 = (const float*)d_in[22];
    const float* r1w2 = (const float*)d_in[23];
    const float* r1b2 = (const float*)d_in[24];
    float* out = (float*)d_out;

    float* ws     = (float*)d_ws;
    float* A      = ws;                  // 3*128*64   = 24576
    float* Bm     = A      + 24576;      //              24576
    float* Ab     = Bm     + 24576;      // 3*64       = 192
    float* Bb     = Ab     + 192;        //              192
    float* hfirst = Bb     + 192;        // 768*64     = 49152
    float* hA     = hfirst + 49152;      //              49152
    float* hB     = hA     + 49152;      //              49152
    float* mask   = hB     + 49152;      //              768
    float* wihT   = mask   + 768;        // 64*192     = 12288
    float* whhT   = wihT   + 12288;      //              12288
    float* accum  = whhT   + 12288;      // 16*128     = 2048
    unsigned* cnt = (unsigned*)(accum + 2048);  // 16 (+pad to 64)
    float* relu2T = accum  + 2048 + 64;  // 36864*128  = 4718592
    // total ~ 4.94M floats = 18.9 MiB

    k_mlp_prep<<<1545, 256, 0, stream>>>(e, mw0, mb0, mw1, mb1, mw2, mb2, h0,
                                         wih, whh, relu2T,
                                         A, Bm, Ab, Bb, hfirst, mask,
                                         wihT, whhT, accum, cnt);
    k_layer<<<768, 256, 0, stream>>>(hfirst, hA, relu2T, A, Bm, Ab, Bb, g, mask,
                                     wihT, whhT, bih, bhh);
    k_layer<<<768, 256, 0, stream>>>(hA, hB, relu2T, A, Bm, Ab, Bb, g, mask,
                                     wihT, whhT, bih, bhh);
    k_layer<<<768, 256, 0, stream>>>(hB, hA, relu2T, A, Bm, Ab, Bb, g, mask,
                                     wihT, whhT, bih, bhh);
    k_read_final<<<192, 256, 0, stream>>>(hfirst, hA, mask,
                                          r0w0, r0b0, r0w1, r0b1, r0w2, r0b2,
                                          r1w0, r1b0, r1w1, r1b1, r1w2, r1b2,
                                          accum, cnt, out);
}

// Round 7
// 192.824 us; speedup vs baseline: 8.1842x; 1.1563x over previous
//
#include <hip/hip_runtime.h>
#include <cmath>

#define B_ 16
#define N_ 48

__device__ __forceinline__ float sigmoidf_(float x){ return 1.0f/(1.0f+expf(-x)); }

// ---------------------------------------------------------------------------
// K1: blocks 0..575: edge MLP, row-order, 64 edges/block (R0-verified config),
//     contiguous row-major relu2[e][c] writes.
//     blocks 576..968: prep (A/Bm/Ab/Bb sums, hfirst, mask, wihT/whhT,
//     zero accum/cnt).
// ---------------------------------------------------------------------------
__global__ __launch_bounds__(256) void k_mlp_prep(
    const float* __restrict__ ein, const float* __restrict__ w0, const float* __restrict__ b0,
    const float* __restrict__ w1, const float* __restrict__ b1,
    const float* __restrict__ w2, const float* __restrict__ b2,
    const float* __restrict__ h0,
    const float* __restrict__ wih, const float* __restrict__ whh,
    float* __restrict__ relu2,
    float* __restrict__ A, float* __restrict__ Bm,
    float* __restrict__ Ab, float* __restrict__ Bb,
    float* __restrict__ hfirst, float* __restrict__ mask,
    float* __restrict__ wihT, float* __restrict__ whhT,
    float* __restrict__ accum, unsigned* __restrict__ cnt)
{
    __shared__ __align__(16) float x1s[64*132];

    if (blockIdx.x >= 576){
        int idx = (blockIdx.x - 576)*256 + threadIdx.x;
        if (idx < 24576) {
            int r = idx >> 13;          // 0..2
            int c = (idx >> 6) & 127;
            int m = idx & 63;
            int t = 48 - 16*r;
            const float* src = w2 + c*4096 + m*64;
            float a = 0.f, b = 0.f;
            for (int k = 0; k < 64; k++){ float v = src[k]; if (k < t) a += v; else b += v; }
            A[idx] = a; Bm[idx] = b;
        } else if (idx < 24768) {
            int i2 = idx - 24576;
            int r = i2 >> 6, m = i2 & 63;
            int t = 48 - 16*r;
            const float* src = b2 + m*64;
            float a = 0.f, b = 0.f;
            for (int k = 0; k < 64; k++){ float v = src[k]; if (k < t) a += v; else b += v; }
            Ab[i2] = a; Bb[i2] = b;
        } else if (idx < 73920) {
            int i3 = idx - 24768;
            int node = i3 >> 6, m = i3 & 63;
            hfirst[i3] = (m < 32) ? h0[node*32 + m] : 0.f;
            if (m == 0) {
                float s = 0.f;
                for (int k = 0; k < 32; k++) s += h0[node*32 + k];
                mask[node] = (s > 0.f) ? 1.f : 0.f;
            }
        } else if (idx < 98496) {
            int i4 = idx - 73920;
            if (i4 < 12288) {
                int k = i4 / 192, col = i4 - k*192;
                wihT[i4] = wih[col*64 + k];
            } else {
                int i5 = i4 - 12288;
                int k = i5 / 192, col = i5 - k*192;
                whhT[i5] = whh[col*64 + k];
            }
        } else if (idx < 100544) {
            accum[idx - 98496] = 0.f;
        } else if (idx < 100560) {
            cnt[idx - 100544] = 0u;
        }
        return;
    }

    int tid = threadIdx.x;
    int et = tid & 15, o0 = (tid >> 4) * 8;
    size_t e0 = (size_t)blockIdx.x * 64;

    // ---- layer 1 ----
    float acc[4][8];
    {
        float4 ba = *(const float4*)&b0[o0];
        float4 bb = *(const float4*)&b0[o0 + 4];
        #pragma unroll
        for (int q = 0; q < 4; q++){
            acc[q][0]=ba.x; acc[q][1]=ba.y; acc[q][2]=ba.z; acc[q][3]=ba.w;
            acc[q][4]=bb.x; acc[q][5]=bb.y; acc[q][6]=bb.z; acc[q][7]=bb.w;
        }
    }
    #pragma unroll
    for (int i4 = 0; i4 < 4; i4++){
        float4 ev[4];
        #pragma unroll
        for (int q = 0; q < 4; q++)
            ev[q] = *(const float4*)&ein[(e0 + q*16 + et)*16 + i4*4];
        #pragma unroll
        for (int d = 0; d < 4; d++){
            int i = i4*4 + d;
            float4 wa = *(const float4*)&w0[i*128 + o0];
            float4 wb = *(const float4*)&w0[i*128 + o0 + 4];
            #pragma unroll
            for (int q = 0; q < 4; q++){
                float xi = (d==0) ? ev[q].x : (d==1) ? ev[q].y : (d==2) ? ev[q].z : ev[q].w;
                acc[q][0] += xi*wa.x; acc[q][1] += xi*wa.y;
                acc[q][2] += xi*wa.z; acc[q][3] += xi*wa.w;
                acc[q][4] += xi*wb.x; acc[q][5] += xi*wb.y;
                acc[q][6] += xi*wb.z; acc[q][7] += xi*wb.w;
            }
        }
    }
    #pragma unroll
    for (int q = 0; q < 4; q++){
        int el = q*16 + et;
        *(float4*)&x1s[el*132 + o0] =
            make_float4(fmaxf(acc[q][0],0.f), fmaxf(acc[q][1],0.f),
                        fmaxf(acc[q][2],0.f), fmaxf(acc[q][3],0.f));
        *(float4*)&x1s[el*132 + o0 + 4] =
            make_float4(fmaxf(acc[q][4],0.f), fmaxf(acc[q][5],0.f),
                        fmaxf(acc[q][6],0.f), fmaxf(acc[q][7],0.f));
    }
    __syncthreads();

    // ---- layer 2 (mw1 rows direct; same accumulation order as w1T version) ----
    float a2[4][8];
    {
        float4 ba = *(const float4*)&b1[o0];
        float4 bb = *(const float4*)&b1[o0 + 4];
        #pragma unroll
        for (int q = 0; q < 4; q++){
            a2[q][0]=ba.x; a2[q][1]=ba.y; a2[q][2]=ba.z; a2[q][3]=ba.w;
            a2[q][4]=bb.x; a2[q][5]=bb.y; a2[q][6]=bb.z; a2[q][7]=bb.w;
        }
    }
    for (int i4 = 0; i4 < 32; i4++){
        int i = i4*4;
        float4 w0a = *(const float4*)&w1[(size_t)(i+0)*128 + o0];
        float4 w0b = *(const float4*)&w1[(size_t)(i+0)*128 + o0 + 4];
        float4 w1a = *(const float4*)&w1[(size_t)(i+1)*128 + o0];
        float4 w1b = *(const float4*)&w1[(size_t)(i+1)*128 + o0 + 4];
        float4 w2a = *(const float4*)&w1[(size_t)(i+2)*128 + o0];
        float4 w2b = *(const float4*)&w1[(size_t)(i+2)*128 + o0 + 4];
        float4 w3a = *(const float4*)&w1[(size_t)(i+3)*128 + o0];
        float4 w3b = *(const float4*)&w1[(size_t)(i+3)*128 + o0 + 4];
        float4 xv[4];
        #pragma unroll
        for (int q = 0; q < 4; q++)
            xv[q] = *(const float4*)&x1s[(q*16 + et)*132 + i];
        #pragma unroll
        for (int q = 0; q < 4; q++){
            float4 x = xv[q];
            a2[q][0] += x.x*w0a.x + x.y*w1a.x + x.z*w2a.x + x.w*w3a.x;
            a2[q][1] += x.x*w0a.y + x.y*w1a.y + x.z*w2a.y + x.w*w3a.y;
            a2[q][2] += x.x*w0a.z + x.y*w1a.z + x.z*w2a.z + x.w*w3a.z;
            a2[q][3] += x.x*w0a.w + x.y*w1a.w + x.z*w2a.w + x.w*w3a.w;
            a2[q][4] += x.x*w0b.x + x.y*w1b.x + x.z*w2b.x + x.w*w3b.x;
            a2[q][5] += x.x*w0b.y + x.y*w1b.y + x.z*w2b.y + x.w*w3b.y;
            a2[q][6] += x.x*w0b.z + x.y*w1b.z + x.z*w2b.z + x.w*w3b.z;
            a2[q][7] += x.x*w0b.w + x.y*w1b.w + x.z*w2b.w + x.w*w3b.w;
        }
    }
    #pragma unroll
    for (int q = 0; q < 4; q++){
        size_t e = e0 + q*16 + et;
        float4 s0 = make_float4(fmaxf(a2[q][0],0.f), fmaxf(a2[q][1],0.f),
                                fmaxf(a2[q][2],0.f), fmaxf(a2[q][3],0.f));
        float4 s1 = make_float4(fmaxf(a2[q][4],0.f), fmaxf(a2[q][5],0.f),
                                fmaxf(a2[q][6],0.f), fmaxf(a2[q][7],0.f));
        *(float4*)&relu2[e*128 + o0]     = s0;
        *(float4*)&relu2[e*128 + o0 + 4] = s1;
    }
}

// ---------------------------------------------------------------------------
// K2: message-passing layer (R0-verified; relu2 row-major, strided i-reads)
// ---------------------------------------------------------------------------
__global__ __launch_bounds__(256) void k_layer(
    const float* __restrict__ hin, float* __restrict__ hout,
    const float* __restrict__ relu2,
    const float* __restrict__ A, const float* __restrict__ Bm,
    const float* __restrict__ Ab, const float* __restrict__ Bb,
    const float* __restrict__ g, const float* __restrict__ mask,
    const float* __restrict__ wihT, const float* __restrict__ whhT,
    const float* __restrict__ bih, const float* __restrict__ bhh)
{
    int bj = blockIdx.x;
    int b = bj / 48, j = bj - b*48;
    int r = j % 3;
    int p0 = j + j/3;
    int tid = threadIdx.x;
    int base = b*48;
    __shared__ float hs[64], wAs[48], wBs[48];
    __shared__ float pU[2][128], pV[2][128];
    __shared__ float Us[128], Vs[128];
    __shared__ float pC[4][64];
    __shared__ float sAB[2];
    __shared__ float aggs[64], gi[192], gh[192];

    if (tid < 64) hs[tid] = hin[(size_t)bj*64 + tid];
    else if (tid < 112){
        int i = tid - 64;
        int node = base + i;
        float gv = g[(size_t)node*48 + j];
        wAs[i] = gv * hin[(size_t)node*64 + p0];
        wBs[i] = gv * hin[(size_t)node*64 + p0 + 1];
    }
    __syncthreads();
    if (tid < 2){
        const float* src = tid ? wBs : wAs;
        float s = 0.f;
        for (int i = 0; i < 48; i++) s += src[i];
        sAB[tid] = s;
    }
    {
        int c = tid & 127, half = tid >> 7;
        const float* r2b = relu2 + ((size_t)base*48 + j)*128 + c;  // i-stride 6144
        float aU = 0.f, aV = 0.f;
        for (int ii = 0; ii < 24; ii++){
            int i = half*24 + ii;
            float v = r2b[(size_t)i*6144];
            aU += wAs[i]*v; aV += wBs[i]*v;
        }
        pU[half][c] = aU; pV[half][c] = aV;
    }
    __syncthreads();
    if (tid < 128){ Us[tid] = pU[0][tid] + pU[1][tid]; Vs[tid] = pV[0][tid] + pV[1][tid]; }
    __syncthreads();
    {
        int m = tid & 63, cg = tid >> 6;
        const float* Arp = A  + r*8192 + m;
        const float* Brp = Bm + r*8192 + m;
        float a = 0.f;
        for (int cc = 0; cc < 32; cc++){
            int c = cg*32 + cc;
            a += Us[c]*Arp[c*64] + Vs[c]*Brp[c*64];
        }
        pC[cg][m] = a;
    }
    __syncthreads();
    if (tid < 64){
        aggs[tid] = pC[0][tid] + pC[1][tid] + pC[2][tid] + pC[3][tid]
                  + sAB[0]*Ab[r*64 + tid] + sAB[1]*Bb[r*64 + tid];
    }
    __syncthreads();
    if (tid < 192){
        float gacc = bih[tid], hacc = bhh[tid];
        for (int k = 0; k < 64; k++){
            gacc += aggs[k] * wihT[k*192 + tid];
            hacc += hs[k]   * whhT[k*192 + tid];
        }
        gi[tid] = gacc; gh[tid] = hacc;
    }
    __syncthreads();
    if (tid < 64){
        float rr = sigmoidf_(gi[tid] + gh[tid]);
        float zz = sigmoidf_(gi[64+tid] + gh[64+tid]);
        float nn = tanhf(gi[128+tid] + rr*gh[128+tid]);
        float hnew = (1.f - zz)*nn + zz*hs[tid];
        hout[(size_t)bj*64 + tid] = mask[bj] * hnew;
    }
}

// ---------------------------------------------------------------------------
// k_read_final: readout, 192 blocks (16 batches x 12 groups of 4 nodes),
// atomic accumulate + last-block sigmoid (R6-verified).
// ---------------------------------------------------------------------------
__device__ __forceinline__ void rd_layer(
    const float* __restrict__ Xs, const float* __restrict__ W,
    const float* __restrict__ bias, float* __restrict__ Ys,
    int dim, int o, int ng, bool do_relu)
{
    float a0 = bias[o];
    float a1 = a0;
    for (int i = 0; i < dim; i += 4){
        float w0 = W[(size_t)(i+0)*128 + o];
        float w1 = W[(size_t)(i+1)*128 + o];
        float w2 = W[(size_t)(i+2)*128 + o];
        float w3 = W[(size_t)(i+3)*128 + o];
        const float4 x0 = *(const float4*)&Xs[ng*128 + i];
        const float4 x1 = *(const float4*)&Xs[(ng+2)*128 + i];
        a0 += x0.x*w0 + x0.y*w1 + x0.z*w2 + x0.w*w3;
        a1 += x1.x*w0 + x1.y*w1 + x1.z*w2 + x1.w*w3;
    }
    if (do_relu){ a0 = fmaxf(a0, 0.f); a1 = fmaxf(a1, 0.f); }
    Ys[ng*128 + o] = a0;
    Ys[(ng+2)*128 + o] = a1;
}

__global__ __launch_bounds__(256) void k_read_final(
    const float* __restrict__ hfirst, const float* __restrict__ hT,
    const float* __restrict__ mask,
    const float* __restrict__ w00, const float* __restrict__ b00,
    const float* __restrict__ w01, const float* __restrict__ b01,
    const float* __restrict__ w02, const float* __restrict__ b02,
    const float* __restrict__ w10, const float* __restrict__ b10,
    const float* __restrict__ w11, const float* __restrict__ b11,
    const float* __restrict__ w12, const float* __restrict__ b12,
    float* __restrict__ accum, unsigned* __restrict__ cnt,
    float* __restrict__ out)
{
    __shared__ __align__(16) float xs[4*128];
    __shared__ __align__(16) float ys[4*128];
    __shared__ __align__(16) float zs[4*128];
    __shared__ __align__(16) float os0[4*128];
    __shared__ float mS[4];
    __shared__ unsigned fin;
    int tid = threadIdx.x;
    int b = blockIdx.x / 12, gg = blockIdx.x - b*12;
    int node0 = b*48 + gg*4;
    int o = tid & 127, ng = tid >> 7;
    if (tid < 4) mS[tid] = mask[node0 + tid];
    for (int i = tid; i < 4*128; i += 256){
        int r = i >> 7, c = i & 127;
        xs[i] = (c < 64) ? hfirst[(size_t)(node0+r)*64 + c]
                         : hT[(size_t)(node0+r)*64 + (c - 64)];
    }
    __syncthreads();
    rd_layer(xs,      w00, b00, ys,  128, o, ng, true);  __syncthreads();
    rd_layer(ys,      w01, b01, zs,  128, o, ng, true);  __syncthreads();
    rd_layer(zs,      w02, b02, os0, 128, o, ng, false); __syncthreads();
    rd_layer(xs + 64, w10, b10, ys,  64,  o, ng, true);  __syncthreads();
    rd_layer(ys,      w11, b11, zs,  128, o, ng, true);  __syncthreads();
    {
        float a0 = b12[o];
        float a1 = a0;
        for (int i = 0; i < 128; i += 4){
            float w0 = w12[(size_t)(i+0)*128 + o];
            float w1 = w12[(size_t)(i+1)*128 + o];
            float w2 = w12[(size_t)(i+2)*128 + o];
            float w3 = w12[(size_t)(i+3)*128 + o];
            const float4 x0 = *(const float4*)&zs[ng*128 + i];
            const float4 x1 = *(const float4*)&zs[(ng+2)*128 + i];
            a0 += x0.x*w0 + x0.y*w1 + x0.z*w2 + x0.w*w3;
            a1 += x1.x*w0 + x1.y*w1 + x1.z*w2 + x1.w*w3;
        }
        float s = mS[ng]   * os0[ng*128 + o]     * a0
                + mS[ng+2] * os0[(ng+2)*128 + o] * a1;
        __syncthreads();
        ys[ng*128 + o] = s;
    }
    __syncthreads();
    if (tid < 128)
        atomicAdd(&accum[(size_t)b*128 + tid], ys[tid] + ys[128 + tid]);
    __syncthreads();
    if (tid == 0){
        __threadfence();
        fin = atomicAdd(&cnt[b], 1u);
    }
    __syncthreads();
    if (fin == 11u && tid < 128){
        float v = atomicAdd(&accum[(size_t)b*128 + tid], 0.f);  // coherent fetch
        out[(size_t)b*128 + tid] = 1.0f / (1.0f + expf(-v));
    }
}

// ---------------------------------------------------------------------------
extern "C" void kernel_launch(void* const* d_in, const int* in_sizes, int n_in,
                              void* d_out, int out_size, void* d_ws, size_t ws_size,
                              hipStream_t stream)
{
    (void)in_sizes; (void)n_in; (void)out_size; (void)ws_size;
    const float* g    = (const float*)d_in[0];
    const float* h0   = (const float*)d_in[1];
    const float* e    = (const float*)d_in[2];
    const float* mw0  = (const float*)d_in[3];
    const float* mb0  = (const float*)d_in[4];
    const float* mw1  = (const float*)d_in[5];
    const float* mb1  = (const float*)d_in[6];
    const float* mw2  = (const float*)d_in[7];
    const float* mb2  = (const float*)d_in[8];
    const float* wih  = (const float*)d_in[9];
    const float* whh  = (const float*)d_in[10];
    const float* bih  = (const float*)d_in[11];
    const float* bhh  = (const float*)d_in[12];
    const float* r0w0 = (const float*)d_in[13];
    const float* r0b0 = (const float*)d_in[14];
    const float* r0w1 = (const float*)d_in[15];
    const float* r0b1 = (const float*)d_in[16];
    const float* r0w2 = (const float*)d_in[17];
    const float* r0b2 = (const float*)d_in[18];
    const float* r1w0 = (const float*)d_in[19];
    const float* r1b0 = (const float*)d_in[20];
    const float* r1w1 = (const float*)d_in[21];
    const float* r1b1 = (const float*)d_in[22];
    const float* r1w2 = (const float*)d_in[23];
    const float* r1b2 = (const float*)d_in[24];
    float* out = (float*)d_out;

    float* ws     = (float*)d_ws;
    float* A      = ws;                  // 3*128*64   = 24576
    float* Bm     = A      + 24576;      //              24576
    float* Ab     = Bm     + 24576;      // 3*64       = 192
    float* Bb     = Ab     + 192;        //              192
    float* hfirst = Bb     + 192;        // 768*64     = 49152
    float* hA     = hfirst + 49152;      //              49152
    float* hB     = hA     + 49152;      //              49152
    float* mask   = hB     + 49152;      //              768
    float* wihT   = mask   + 768;        // 64*192     = 12288
    float* whhT   = wihT   + 12288;      //              12288
    float* accum  = whhT   + 12288;      // 16*128     = 2048
    unsigned* cnt = (unsigned*)(accum + 2048);  // 16 (+pad to 64)
    float* relu2  = accum  + 2048 + 64;  // 36864*128  = 4718592
    // total ~ 4.99M floats = 19.0 MiB

    k_mlp_prep<<<969, 256, 0, stream>>>(e, mw0, mb0, mw1, mb1, mw2, mb2, h0,
                                        wih, whh, relu2,
                                        A, Bm, Ab, Bb, hfirst, mask,
                                        wihT, whhT, accum, cnt);
    k_layer<<<768, 256, 0, stream>>>(hfirst, hA, relu2, A, Bm, Ab, Bb, g, mask,
                                     wihT, whhT, bih, bhh);
    k_layer<<<768, 256, 0, stream>>>(hA, hB, relu2, A, Bm, Ab, Bb, g, mask,
                                     wihT, whhT, bih, bhh);
    k_layer<<<768, 256, 0, stream>>>(hB, hA, relu2, A, Bm, Ab, Bb, g, mask,
                                     wihT, whhT, bih, bhh);
    k_read_final<<<192, 256, 0, stream>>>(hfirst, hA, mask,
                                          r0w0, r0b0, r0w1, r0b1, r0w2, r0b2,
                                          r1w0, r1b0, r1w1, r1b1, r1w2, r1b2,
                                          accum, cnt, out);
}